// Round 1
// baseline (158.538 us; speedup 1.0000x reference)
//
#include <hip/hip_runtime.h>

// SE(3) exp + point transform. Memory-bound: 176 MB traffic, ~28 us floor @6.3 TB/s.
// Each thread: 4 points = 3 float4 loads + 3 float4 stores. R,t recomputed
// per-thread from block-uniform dofs (scalar loads, ~40 flops, free).

__global__ __launch_bounds__(256) void se3_apply_kernel(
    const float* __restrict__ X,      // (BT, N, 3) flattened
    const float* __restrict__ dofs,   // (BT, 6)
    float* __restrict__ out,
    int n3,                            // floats per (b,t) = N*3
    int blocksPerBT)
{
    const int bt    = blockIdx.x / blocksPerBT;
    const int chunk = blockIdx.x - bt * blocksPerBT;

    // ---- SE(3) exponential (block-uniform) ----
    const float* d = dofs + bt * 6;
    const float tx = d[0], ty = d[1], tz = d[2];
    const float wx = d[3], wy = d[4], wz = d[5];

    const float nrm2  = wx * wx + wy * wy + wz * wz;
    const float th2   = fmaxf(nrm2, 1e-4f);      // jnp.clip(nrms, 1e-4) (min only)
    const float theta = sqrtf(th2);
    const float st = sinf(theta);
    const float ct = cosf(theta);
    const float f1 = st / theta;
    const float f2 = (1.0f - ct) / th2;
    const float f3 = (theta - st) / (th2 * theta);

    const float xx = wx * wx, yy = wy * wy, zz = wz * wz;
    const float xy = wx * wy, xz = wx * wz, yz = wy * wz;

    // R = I + f1*H + f2*H^2
    const float R00 = 1.0f - f2 * (yy + zz);
    const float R01 = f2 * xy - f1 * wz;
    const float R02 = f2 * xz + f1 * wy;
    const float R10 = f2 * xy + f1 * wz;
    const float R11 = 1.0f - f2 * (xx + zz);
    const float R12 = f2 * yz - f1 * wx;
    const float R20 = f2 * xz - f1 * wy;
    const float R21 = f2 * yz + f1 * wx;
    const float R22 = 1.0f - f2 * (xx + yy);

    // V = I + f2*H + f3*H^2 ; t = V @ t_log
    const float V00 = 1.0f - f3 * (yy + zz);
    const float V01 = f3 * xy - f2 * wz;
    const float V02 = f3 * xz + f2 * wy;
    const float V10 = f3 * xy + f2 * wz;
    const float V11 = 1.0f - f3 * (xx + zz);
    const float V12 = f3 * yz - f2 * wx;
    const float V20 = f3 * xz - f2 * wy;
    const float V21 = f3 * yz + f2 * wx;
    const float V22 = 1.0f - f3 * (xx + yy);

    const float Tx = V00 * tx + V01 * ty + V02 * tz;
    const float Ty = V10 * tx + V11 * ty + V12 * tz;
    const float Tz = V20 * tx + V21 * ty + V22 * tz;

    // ---- point transform: 4 points / thread ----
    const int tIdx = chunk * (int)blockDim.x + (int)threadIdx.x;
    const int fOff = tIdx * 12;                 // float offset within this bt
    if (fOff + 12 > n3) return;

    const long long base = (long long)bt * (long long)n3 + (long long)fOff;
    const float4* __restrict__ Xp = (const float4*)(X + base);
    float4* __restrict__ Op       = (float4*)(out + base);

    const float4 v0 = Xp[0];
    const float4 v1 = Xp[1];
    const float4 v2 = Xp[2];

#define SE3_TR(px, py, pz, qx, qy, qz)                                   \
    qx = fmaf(R00, px, fmaf(R01, py, fmaf(R02, pz, Tx)));                \
    qy = fmaf(R10, px, fmaf(R11, py, fmaf(R12, pz, Ty)));                \
    qz = fmaf(R20, px, fmaf(R21, py, fmaf(R22, pz, Tz)));

    float q0x, q0y, q0z, q1x, q1y, q1z, q2x, q2y, q2z, q3x, q3y, q3z;
    SE3_TR(v0.x, v0.y, v0.z, q0x, q0y, q0z);
    SE3_TR(v0.w, v1.x, v1.y, q1x, q1y, q1z);
    SE3_TR(v1.z, v1.w, v2.x, q2x, q2y, q2z);
    SE3_TR(v2.y, v2.z, v2.w, q3x, q3y, q3z);
#undef SE3_TR

    Op[0] = make_float4(q0x, q0y, q0z, q1x);
    Op[1] = make_float4(q1y, q1z, q2x, q2y);
    Op[2] = make_float4(q2z, q3x, q3y, q3z);
}

extern "C" void kernel_launch(void* const* d_in, const int* in_sizes, int n_in,
                              void* d_out, int out_size, void* d_ws, size_t ws_size,
                              hipStream_t stream) {
    const float* X    = (const float*)d_in[0];
    const float* dofs = (const float*)d_in[1];
    float* out        = (float*)d_out;

    const int BT = in_sizes[1] / 6;            // 64*28 = 1792
    const int n3 = in_sizes[0] / BT;           // 4096*3 = 12288 floats per bt

    const int threadsPerBT = (n3 + 11) / 12;   // 4 points (12 floats) per thread -> 1024
    const int block = 256;
    const int blocksPerBT = (threadsPerBT + block - 1) / block;  // 4

    dim3 grid((unsigned)(BT * blocksPerBT));   // 7168 blocks
    se3_apply_kernel<<<grid, block, 0, stream>>>(X, dofs, out, n3, blocksPerBT);
}

// Round 2
// 156.855 us; speedup vs baseline: 1.0107x; 1.0107x over previous
//
#include <hip/hip_runtime.h>

// SE(3) exp + point transform, LDS-staged for perfect global coalescing.
// Global pattern: lane-contiguous float4 both directions (the 6.3 TB/s pattern).
// LDS compute-phase: stride-3-float addresses -> conflict-free (3 coprime 32;
// half-wave 2-way aliasing is free per m136).
// Tile = 1024 points = 3072 floats = 12 KB LDS; block = 256 threads, 4 pts/thread.

__global__ __launch_bounds__(256) void se3_apply_kernel(
    const float* __restrict__ X,      // (BT, N, 3) flattened
    const float* __restrict__ dofs,   // (BT, 6)
    float* __restrict__ out,
    int n3,                            // floats per (b,t) = N*3
    int tilesPerBT)
{
    __shared__ float lds[3072];

    const int bt   = blockIdx.x / tilesPerBT;
    const int tile = blockIdx.x - bt * tilesPerBT;
    const int t    = threadIdx.x;

    const long long baseF = (long long)bt * (long long)n3 + (long long)tile * 3072;
    const int f4InBT   = tile * 768;            // float4 index of tile start within bt
    const int n4       = n3 >> 2;               // float4 count per bt
    const float4* __restrict__ Xp = (const float4*)(X + baseF);
    float4* __restrict__ Op       = (float4*)(out + baseF);
    float4* lds4 = (float4*)lds;

    // ---- stage-in: lane-contiguous float4 loads (issue first, overlap with setup) ----
    float4 v0, v1, v2;
    const bool g0 = (f4InBT + t        ) < n4;
    const bool g1 = (f4InBT + t + 256  ) < n4;
    const bool g2 = (f4InBT + t + 512  ) < n4;
    if (g0) v0 = Xp[t];
    if (g1) v1 = Xp[t + 256];
    if (g2) v2 = Xp[t + 512];

    // ---- SE(3) exponential (block-uniform; overlaps global-load latency) ----
    const float* d = dofs + bt * 6;
    const float tx = d[0], ty = d[1], tz = d[2];
    const float wx = d[3], wy = d[4], wz = d[5];

    const float nrm2  = wx * wx + wy * wy + wz * wz;
    const float th2   = fmaxf(nrm2, 1e-4f);      // jnp.clip(nrms, 1e-4) (min only)
    const float theta = sqrtf(th2);
    const float st = sinf(theta);
    const float ct = cosf(theta);
    const float f1 = st / theta;
    const float f2 = (1.0f - ct) / th2;
    const float f3 = (theta - st) / (th2 * theta);

    const float xx = wx * wx, yy = wy * wy, zz = wz * wz;
    const float xy = wx * wy, xz = wx * wz, yz = wy * wz;

    const float R00 = 1.0f - f2 * (yy + zz);
    const float R01 = f2 * xy - f1 * wz;
    const float R02 = f2 * xz + f1 * wy;
    const float R10 = f2 * xy + f1 * wz;
    const float R11 = 1.0f - f2 * (xx + zz);
    const float R12 = f2 * yz - f1 * wx;
    const float R20 = f2 * xz - f1 * wy;
    const float R21 = f2 * yz + f1 * wx;
    const float R22 = 1.0f - f2 * (xx + yy);

    const float V00 = 1.0f - f3 * (yy + zz);
    const float V01 = f3 * xy - f2 * wz;
    const float V02 = f3 * xz + f2 * wy;
    const float V10 = f3 * xy + f2 * wz;
    const float V11 = 1.0f - f3 * (xx + zz);
    const float V12 = f3 * yz - f2 * wx;
    const float V20 = f3 * xz - f2 * wy;
    const float V21 = f3 * yz + f2 * wx;
    const float V22 = 1.0f - f3 * (xx + yy);

    const float Tx = V00 * tx + V01 * ty + V02 * tz;
    const float Ty = V10 * tx + V11 * ty + V12 * tz;
    const float Tz = V20 * tx + V21 * ty + V22 * tz;

    // ---- park loads in LDS ----
    if (g0) lds4[t]       = v0;
    if (g1) lds4[t + 256] = v1;
    if (g2) lds4[t + 512] = v2;
    __syncthreads();

    // ---- compute in-place: 4 points/thread, strided by 256 points ----
    // addr = 3*(t + 256*j) floats: conflict-free banks, in-place safe
    // (each float location touched by exactly one thread).
#pragma unroll
    for (int j = 0; j < 4; ++j) {
        const int p = 3 * (t + 256 * j);
        const float px = lds[p + 0];
        const float py = lds[p + 1];
        const float pz = lds[p + 2];
        lds[p + 0] = fmaf(R00, px, fmaf(R01, py, fmaf(R02, pz, Tx)));
        lds[p + 1] = fmaf(R10, px, fmaf(R11, py, fmaf(R12, pz, Ty)));
        lds[p + 2] = fmaf(R20, px, fmaf(R21, py, fmaf(R22, pz, Tz)));
    }
    __syncthreads();

    // ---- stage-out: lane-contiguous float4 stores ----
    if (g0) Op[t]       = lds4[t];
    if (g1) Op[t + 256] = lds4[t + 256];
    if (g2) Op[t + 512] = lds4[t + 512];
}

extern "C" void kernel_launch(void* const* d_in, const int* in_sizes, int n_in,
                              void* d_out, int out_size, void* d_ws, size_t ws_size,
                              hipStream_t stream) {
    const float* X    = (const float*)d_in[0];
    const float* dofs = (const float*)d_in[1];
    float* out        = (float*)d_out;

    const int BT = in_sizes[1] / 6;            // 64*28 = 1792
    const int n3 = in_sizes[0] / BT;           // 4096*3 = 12288 floats per bt

    const int tilesPerBT = (n3 + 3071) / 3072; // 4 for N=4096

    dim3 grid((unsigned)(BT * tilesPerBT));    // 7168 blocks
    se3_apply_kernel<<<grid, 256, 0, stream>>>(X, dofs, out, n3, tilesPerBT);
}